// Round 7
// baseline (53761.011 us; speedup 1.0000x reference)
//
#include <hip/hip_runtime.h>
#include <cstdint>

typedef uint32_t u32;
typedef _Float16 f16;
typedef f16 f16x2 __attribute__((ext_vector_type(2)));
typedef f16 f16x8 __attribute__((ext_vector_type(8)));
typedef float f32x4 __attribute__((ext_vector_type(4)));

static __device__ __forceinline__ u32 pack2(float a, float b) {
    f16x2 v;
    v.x = (f16)a;
    v.y = (f16)b;
    return __builtin_bit_cast(u32, v);
}

static __device__ __forceinline__ float dot2(u32 a, u32 b, float c) {
    return __builtin_amdgcn_fdot2(__builtin_bit_cast(f16x2, a),
                                  __builtin_bit_cast(f16x2, b), c, false);
}

static __device__ __forceinline__ unsigned short f16bits(float v) {
    return __builtin_bit_cast(unsigned short, (f16)v);
}

// barrier without vmcnt(0) drain (global enc stores must not stall the loop)
#define BAR() asm volatile("s_waitcnt lgkmcnt(0)\n\ts_barrier" ::: "memory")

#define MFMA(A, B, C) __builtin_amdgcn_mfma_f32_16x16x32_f16(A, B, C, 0, 0, 0)

// ---------------------------------------------------------------------------
// RNN kernel: 1 workgroup, 256 threads (4 waves, 1/SIMD), persistent.
// PIPE FLIP vs R6: critical matvec on the VALU (dot2: 2.4x denser than MFMA
// for matvec, ~4cy dep latency vs ~40), slack matvec on the MFMA pipe.
//  - IH (critical, dot2): y_l = relu(Wih_l . cur + pre[l]).
//    Lane: row = w*32 + (lane>>1), kh = lane&1 (64 K-elems each).
//    32 dot2/lane -> 64cy/SIMD issue; 1 DPP reduce.
//  - HH (shadow, MFMA, 2-slot slack): in slot l, write last slot's pending
//    D regs to pre[(l+1)&3], then issue 8 MFMAs computing
//    pre[(l+2)&3] = Whh . y_stable + bias (C seeded with bias).
//    MFMA pipe time (155cy/SIMD) + B-frag latency hide under barriers.
// Weights resident: Wih as dot2 pairs (128 VGPR) + Whh as A-frags (128 VGPR)
// + bias seeds (32). State f16 in LDS ping-pong buf[2][4][64];
// pre[4][128] f32 in LDS. 4 lgkm-only barriers/step.
// ---------------------------------------------------------------------------
__global__ __launch_bounds__(256, 1) void rnn_kernel(
    const float* __restrict__ x0,
    const float* __restrict__ Wih, const float* __restrict__ Whh,
    const float* __restrict__ bih, const float* __restrict__ bhh,
    u32* __restrict__ enc, int T)
{
    __shared__ u32 buf[2][4][64];    // per-layer outputs, f16 pairs
    __shared__ float pre[4][128];    // Whh.hid + biases, f32

    const int tid  = threadIdx.x;
    const int w    = tid >> 6;               // wave 0..3
    const int lane = tid & 63;
    const int rsh  = w * 32 + (lane >> 1);   // IH row
    const int kh   = lane & 1;               // IH k-half (64 elems)
    const int m    = lane & 15;              // HH A row-in-tile
    const int g    = lane >> 4;              // HH k-group / D row-quad

    // ---- resident IH dot2 weights (row rsh, elems kh*64..kh*64+63)
    u32 wih[4][32];
    #pragma unroll
    for (int l = 0; l < 4; ++l) {
        const float* p = Wih + ((size_t)(l * 128 + rsh)) * 128 + kh * 64;
        #pragma unroll
        for (int j = 0; j < 32; ++j)
            wih[l][j] = pack2(p[2 * j], p[2 * j + 1]);
    }

    // ---- resident HH A-frags + bias seeds
    f16x8 hhA[4][2][4];              // [layer][tile][ktile]
    f32x4 biasT[4][2];
    #pragma unroll
    for (int l = 0; l < 4; ++l)
        #pragma unroll
        for (int t = 0; t < 2; ++t) {
            const int row = w * 32 + t * 16 + m;
            #pragma unroll
            for (int kt = 0; kt < 4; ++kt) {
                const float* p = Whh + ((size_t)(l * 128 + row)) * 128
                                     + kt * 32 + g * 8;
                f16x8 v;
                #pragma unroll
                for (int e = 0; e < 8; ++e) v[e] = (f16)p[e];
                hhA[l][t][kt] = v;
            }
            const int r4 = w * 32 + t * 16 + g * 4;
            f32x4 b;
            #pragma unroll
            for (int r = 0; r < 4; ++r)
                b[r] = bih[l * 128 + r4 + r] + bhh[l * 128 + r4 + r];
            biasT[l][t] = b;
        }

    // ---- LDS init: buf[1] = { f16(x), 0, 0, 0 }  (y(-1) state; step 0: p=0)
    if (tid < 64)       buf[1][0][tid] = pack2(x0[2 * tid], x0[2 * tid + 1]);
    else if (tid < 256) ((u32*)buf[1])[tid] = 0u;
    __syncthreads();

    // ---- prologue: pre[0] = Whh_0 . x + b0  (hid_0(-1) = x)
    {
        const u32* sb = &buf[1][0][0];
        f16x8 j0 = *(const f16x8*)(sb + 0 * 16 + g * 4);
        f16x8 j1 = *(const f16x8*)(sb + 1 * 16 + g * 4);
        f16x8 j2 = *(const f16x8*)(sb + 2 * 16 + g * 4);
        f16x8 j3 = *(const f16x8*)(sb + 3 * 16 + g * 4);
        f32x4 t0 = MFMA(hhA[0][0][0], j0, biasT[0][0]);
        t0 = MFMA(hhA[0][0][1], j1, t0);
        t0 = MFMA(hhA[0][0][2], j2, t0);
        t0 = MFMA(hhA[0][0][3], j3, t0);
        f32x4 t1 = MFMA(hhA[0][1][0], j0, biasT[0][1]);
        t1 = MFMA(hhA[0][1][1], j1, t1);
        t1 = MFMA(hhA[0][1][2], j2, t1);
        t1 = MFMA(hhA[0][1][3], j3, t1);
        if (m == 0) {
            *(f32x4*)&pre[0][w * 32 + g * 4] = t0;
            *(f32x4*)&pre[0][w * 32 + 16 + g * 4] = t1;
        }
    }
    // pending for slot 0's write of pre[1]: Whh_1 . 0 + b1 = b1
    f32x4 pa0, pa1;
    f32x4 pb0 = biasT[1][0], pb1 = biasT[1][1];
    BAR();

    // One layer-slot. Critical dot2 IH first; then shadow: write pending D
    // (layer LW=(l+1)&3), read stable B (SHB), issue 8 MFMAs (layer
    // LT=(l+2)&3) into PI*, seeded with bias. 1 lgkm-only barrier.
#define SLOT(l, P, CURB, SHB, LT, LW, PI0, PI1, PW0, PW1, STORE, S) do {      \
        float pr = pre[l][rsh];                                               \
        const u32* _yb = (CURB) + kh * 32;                                    \
        uint4 h0 = *(const uint4*)(_yb + 0);                                  \
        uint4 h1 = *(const uint4*)(_yb + 4);                                  \
        uint4 h2 = *(const uint4*)(_yb + 8);                                  \
        uint4 h3 = *(const uint4*)(_yb + 12);                                 \
        uint4 h4 = *(const uint4*)(_yb + 16);                                 \
        uint4 h5 = *(const uint4*)(_yb + 20);                                 \
        uint4 h6 = *(const uint4*)(_yb + 24);                                 \
        uint4 h7 = *(const uint4*)(_yb + 28);                                 \
        const u32* _wd = wih[l];                                              \
        float va = kh ? 0.f : pr, vb = 0.f, vc = 0.f, vd = 0.f;               \
        va = dot2(h0.x, _wd[0], va);  vb = dot2(h0.y, _wd[1], vb);            \
        vc = dot2(h0.z, _wd[2], vc);  vd = dot2(h0.w, _wd[3], vd);            \
        va = dot2(h1.x, _wd[4], va);  vb = dot2(h1.y, _wd[5], vb);            \
        vc = dot2(h1.z, _wd[6], vc);  vd = dot2(h1.w, _wd[7], vd);            \
        va = dot2(h2.x, _wd[8], va);  vb = dot2(h2.y, _wd[9], vb);            \
        vc = dot2(h2.z, _wd[10], vc); vd = dot2(h2.w, _wd[11], vd);           \
        va = dot2(h3.x, _wd[12], va); vb = dot2(h3.y, _wd[13], vb);           \
        vc = dot2(h3.z, _wd[14], vc); vd = dot2(h3.w, _wd[15], vd);           \
        va = dot2(h4.x, _wd[16], va); vb = dot2(h4.y, _wd[17], vb);           \
        vc = dot2(h4.z, _wd[18], vc); vd = dot2(h4.w, _wd[19], vd);           \
        va = dot2(h5.x, _wd[20], va); vb = dot2(h5.y, _wd[21], vb);           \
        vc = dot2(h5.z, _wd[22], vc); vd = dot2(h5.w, _wd[23], vd);           \
        va = dot2(h6.x, _wd[24], va); vb = dot2(h6.y, _wd[25], vb);           \
        vc = dot2(h6.z, _wd[26], vc); vd = dot2(h6.w, _wd[27], vd);           \
        va = dot2(h7.x, _wd[28], va); vb = dot2(h7.y, _wd[29], vb);           \
        vc = dot2(h7.z, _wd[30], vc); vd = dot2(h7.w, _wd[31], vd);           \
        float v = (va + vb) + (vc + vd);                                      \
        v += __shfl_xor(v, 1);                                                \
        float y = fmaxf(v, 0.f);                                              \
        float yo = __shfl_xor(y, 2);                                          \
        if ((lane & 3) == 0) {                                                \
            u32 pk = pack2(y, yo);                                            \
            buf[P][l][w * 16 + (lane >> 2)] = pk;                             \
            if (STORE)                                                        \
                enc[(size_t)(S) * 64 + w * 16 + (lane >> 2)] = pk;            \
        }                                                                     \
        if (m == 0) {                                                         \
            *(f32x4*)&pre[LW][w * 32 + g * 4] = PW0;                          \
            *(f32x4*)&pre[LW][w * 32 + 16 + g * 4] = PW1;                     \
        }                                                                     \
        const u32* _sb = (SHB);                                               \
        f16x8 j0 = *(const f16x8*)(_sb + 0 * 16 + g * 4);                     \
        f16x8 j1 = *(const f16x8*)(_sb + 1 * 16 + g * 4);                     \
        f16x8 j2 = *(const f16x8*)(_sb + 2 * 16 + g * 4);                     \
        f16x8 j3 = *(const f16x8*)(_sb + 3 * 16 + g * 4);                     \
        PI0 = MFMA(hhA[LT][0][0], j0, biasT[LT][0]);                          \
        PI0 = MFMA(hhA[LT][0][1], j1, PI0);                                   \
        PI0 = MFMA(hhA[LT][0][2], j2, PI0);                                   \
        PI0 = MFMA(hhA[LT][0][3], j3, PI0);                                   \
        PI1 = MFMA(hhA[LT][1][0], j0, biasT[LT][1]);                          \
        PI1 = MFMA(hhA[LT][1][1], j1, PI1);                                   \
        PI1 = MFMA(hhA[LT][1][2], j2, PI1);                                   \
        PI1 = MFMA(hhA[LT][1][3], j3, PI1);                                   \
        BAR();                                                                \
    } while (0)

    for (int s = 0; s < T; s += 2) {
        // parity p=0, q=1
        SLOT(0, 0, &buf[1][3][0], &buf[1][2][0], 2, 1, pa0, pa1, pb0, pb1, 0, s);
        SLOT(1, 0, &buf[0][0][0], &buf[1][3][0], 3, 2, pb0, pb1, pa0, pa1, 0, s);
        SLOT(2, 0, &buf[0][1][0], &buf[0][0][0], 0, 3, pa0, pa1, pb0, pb1, 0, s);
        SLOT(3, 0, &buf[0][2][0], &buf[0][1][0], 1, 0, pb0, pb1, pa0, pa1, 1, s);
        // parity p=1, q=0
        SLOT(0, 1, &buf[0][3][0], &buf[0][2][0], 2, 1, pa0, pa1, pb0, pb1, 0, s + 1);
        SLOT(1, 1, &buf[1][0][0], &buf[0][3][0], 3, 2, pb0, pb1, pa0, pa1, 0, s + 1);
        SLOT(2, 1, &buf[1][1][0], &buf[1][0][0], 0, 3, pa0, pa1, pb0, pb1, 0, s + 1);
        SLOT(3, 1, &buf[1][2][0], &buf[1][1][0], 1, 0, pb0, pb1, pa0, pa1, 1, s + 1);
    }
#undef SLOT
}

// ---------------------------------------------------------------------------
// Heads kernel: grid (3 heads, T/32 row-segments), 256 threads. (unchanged)
// ---------------------------------------------------------------------------
__global__ __launch_bounds__(256) void heads_kernel(
    const u32* __restrict__ enc,
    const float* __restrict__ arw, const float* __restrict__ arb,
    const float* __restrict__ aw,  const float* __restrict__ ab,
    const float* __restrict__ prw, const float* __restrict__ prb,
    const float* __restrict__ pw,  const float* __restrict__ pb,
    const float* __restrict__ mrw, const float* __restrict__ mrb,
    const float* __restrict__ mw,  const float* __restrict__ mb,
    float* __restrict__ out, int T)
{
    const int head = blockIdx.x;
    const int r0 = blockIdx.y * 32;
    if (r0 >= T) return;

    const float *rbw, *rbb, *ow, *ob;
    int od, oc;
    if (head == 0)      { rbw = arw; rbb = arb; ow = aw; ob = ab; od = 8; oc = 0; }
    else if (head == 1) { rbw = prw; rbb = prb; ow = pw; ob = pb; od = 1; oc = 8; }
    else                { rbw = mrw; rbb = mrb; ow = mw; ob = mb; od = 1; oc = 9; }

    __shared__ u32 xs[32][64];
    __shared__ u32 hs[32][64];

    const int tid = threadIdx.x;

    #pragma unroll
    for (int rep = 0; rep < 8; ++rep) {
        int u = tid + rep * 256;
        int row = u >> 6, p = u & 63;
        xs[row][p] = enc[(size_t)(r0 + row) * 64 + p];
    }
    __syncthreads();

    const int j = tid & 127;
    const int rh = tid >> 7;

    float acc[16];
    u32 wreg[64];

#define PACKW(WPTR) do {                                                    \
        const float* _w = (WPTR);                                           \
        _Pragma("unroll")                                                   \
        for (int cc = 0; cc < 16; ++cc) {                                   \
            float4 aa = *(const float4*)(_w + cc * 8);                      \
            float4 bb = *(const float4*)(_w + cc * 8 + 4);                  \
            wreg[cc * 4 + 0] = pack2(aa.x, aa.y);                           \
            wreg[cc * 4 + 1] = pack2(aa.z, aa.w);                           \
            wreg[cc * 4 + 2] = pack2(bb.x, bb.y);                           \
            wreg[cc * 4 + 3] = pack2(bb.z, bb.w);                           \
        }                                                                   \
    } while (0)

#define MM16(SRC) do {                                                      \
        _Pragma("unroll")                                                   \
        for (int r = 0; r < 16; ++r) acc[r] = 0.f;                          \
        _Pragma("unroll")                                                   \
        for (int kp = 0; kp < 16; ++kp) {                                   \
            u32 w0 = wreg[kp * 4 + 0], w1 = wreg[kp * 4 + 1];               \
            u32 w2 = wreg[kp * 4 + 2], w3 = wreg[kp * 4 + 3];               \
            _Pragma("unroll")                                               \
            for (int r = 0; r < 16; ++r) {                                  \
                uint4 x4 = *(const uint4*)(&SRC[rh * 16 + r][kp * 4]);      \
                acc[r] = dot2(x4.x, w0, acc[r]);                            \
                acc[r] = dot2(x4.y, w1, acc[r]);                            \
                acc[r] = dot2(x4.z, w2, acc[r]);                            \
                acc[r] = dot2(x4.w, w3, acc[r]);                            \
            }                                                               \
        }                                                                   \
    } while (0)

    #pragma unroll
    for (int blk = 0; blk < 2; ++blk) {
        PACKW(rbw + (size_t)((blk * 2 + 0) * 128 + j) * 128);
        MM16(xs);
        {
            float b1 = rbb[(blk * 2 + 0) * 128 + j];
            #pragma unroll
            for (int r = 0; r < 16; ++r) {
                float v = acc[r] + b1;
                v = fmaxf(v, 0.2f * v);
                reinterpret_cast<unsigned short*>(&hs[rh * 16 + r][0])[j] = f16bits(v);
            }
        }
        __syncthreads();

        PACKW(rbw + (size_t)((blk * 2 + 1) * 128 + j) * 128);
        MM16(hs);
        {
            float b2 = rbb[(blk * 2 + 1) * 128 + j];
            #pragma unroll
            for (int r = 0; r < 16; ++r) {
                int row = rh * 16 + r;
                unsigned short xb =
                    reinterpret_cast<const unsigned short*>(&xs[row][0])[j];
                float xold = (float)__builtin_bit_cast(f16, xb);
                float v = xold + acc[r] + b2;
                v = fmaxf(v, 0.2f * v);
                reinterpret_cast<unsigned short*>(&xs[row][0])[j] = f16bits(v);
            }
        }
        __syncthreads();
    }

    {
        const int o = tid & 15;
        const int rr = tid >> 4;
        if (o < od) {
            PACKW(ow + (size_t)o * 128);
            float obv = ob[o];
            #pragma unroll
            for (int rs = 0; rs < 2; ++rs) {
                const int row = rr * 2 + rs;
                float a = 0.f;
                #pragma unroll
                for (int kp = 0; kp < 64; ++kp) a = dot2(xs[row][kp], wreg[kp], a);
                out[(size_t)(r0 + row) * 10 + oc + o] = a + obv;
            }
        }
    }
#undef PACKW
#undef MM16
}

extern "C" void kernel_launch(void* const* d_in, const int* in_sizes, int n_in,
                              void* d_out, int out_size, void* d_ws, size_t ws_size,
                              hipStream_t stream)
{
    const float* x   = (const float*)d_in[0];
    const float* Wih = (const float*)d_in[1];
    const float* Whh = (const float*)d_in[2];
    const float* bih = (const float*)d_in[3];
    const float* bhh = (const float*)d_in[4];
    const float* arw = (const float*)d_in[5];
    const float* arb = (const float*)d_in[6];
    const float* aw  = (const float*)d_in[7];
    const float* ab  = (const float*)d_in[8];
    const float* prw = (const float*)d_in[9];
    const float* prb = (const float*)d_in[10];
    const float* pw  = (const float*)d_in[11];
    const float* pb  = (const float*)d_in[12];
    const float* mrw = (const float*)d_in[13];
    const float* mrb = (const float*)d_in[14];
    const float* mw  = (const float*)d_in[15];
    const float* mb  = (const float*)d_in[16];

    const int T = out_size / 10;             // 32768
    u32* enc = (u32*)d_ws;                   // T*64 u32 (f16 pairs) = 8 MB

    rnn_kernel<<<1, 256, 0, stream>>>(x, Wih, Whh, bih, bhh, enc, T);

    heads_kernel<<<dim3(3, (T + 31) / 32), 256, 0, stream>>>(
        enc, arw, arb, aw, ab, prw, prb, pw, pb, mrw, mrb, mw, mb,
        (float*)d_out, T);
}

// Round 8
// 40887.833 us; speedup vs baseline: 1.3148x; 1.3148x over previous
//
#include <hip/hip_runtime.h>
#include <cstdint>

typedef uint32_t u32;
typedef _Float16 f16;
typedef f16 f16x2 __attribute__((ext_vector_type(2)));
typedef f16 f16x8 __attribute__((ext_vector_type(8)));
typedef float f32x4 __attribute__((ext_vector_type(4)));

static __device__ __forceinline__ u32 pack2(float a, float b) {
    f16x2 v;
    v.x = (f16)a;
    v.y = (f16)b;
    return __builtin_bit_cast(u32, v);
}

static __device__ __forceinline__ float dot2(u32 a, u32 b, float c) {
    return __builtin_amdgcn_fdot2(__builtin_bit_cast(f16x2, a),
                                  __builtin_bit_cast(f16x2, b), c, false);
}

static __device__ __forceinline__ unsigned short f16bits(float v) {
    return __builtin_bit_cast(unsigned short, (f16)v);
}

// barrier without vmcnt(0) drain (global enc stores must not stall the loop)
#define BAR() asm volatile("s_waitcnt lgkmcnt(0)\n\ts_barrier" ::: "memory")

#define MFMA(A, B, C) __builtin_amdgcn_mfma_f32_16x16x32_f16(A, B, C, 0, 0, 0)

__global__ void reset_flag(u32* f) { *f = 0u; }

// ---------------------------------------------------------------------------
// RNN kernel. Block 0: the RNN (8 waves, specialized). Blocks 1..255: DVFS
// heater (poll done-flag, ~50% duty FMA spin) — tests the low-clock theory.
//
// Block 0 structure (R6's proven sync skeleton, pipes swapped):
//  - waves 0-3 (IH, critical, VALU dot2): y_l = relu(Wih_l.cur + pre[l] + b).
//    Lane: row = w*32+(lane>>1), kh = lane&1. 32 dot2 + 1 DPP reduce.
//    Seeds pre (raw Whh.hid) + bsum (bias held in 4 VGPRs here).
//  - waves 4-7 (HH, shadow, MFMA pipe): pre[(l+1)&3] written from pending D
//    regs; 8 MFMAs (C=0) for (l+2)&3 on B-frags PREFETCHED one slot early
//    (ping-pong pfA/pfB) so HH LDS reads are also off-critical; prefetch for
//    (l+3)&3 from the same buffer IH reads this slot.
// State f16 in LDS buf[2][4][64]; pre[4][128] f32 raw. 1 lgkm barrier/slot.
// ---------------------------------------------------------------------------
__global__ __launch_bounds__(512, 2) void rnn_kernel(
    const float* __restrict__ x0,
    const float* __restrict__ Wih, const float* __restrict__ Whh,
    const float* __restrict__ bih, const float* __restrict__ bhh,
    u32* __restrict__ enc, u32* __restrict__ flag, int T)
{
    if (blockIdx.x != 0) {
        // ---------------- heater: keep DVFS up until block 0 finishes ----
        float a0 = 1.0f + (float)threadIdx.x;
        while (__hip_atomic_load(flag, __ATOMIC_RELAXED,
                                 __HIP_MEMORY_SCOPE_AGENT) == 0u) {
            #pragma unroll
            for (int i = 0; i < 128; ++i)
                a0 = __builtin_fmaf(a0, 0.9999999f, 1.0e-7f);
            __builtin_amdgcn_s_sleep(2);
        }
        if (a0 == 123456.789f) flag[1] = (u32)a0;  // never true; keeps a0 live
        return;
    }

    __shared__ u32 buf[2][4][64];    // per-layer outputs, f16 pairs
    __shared__ float pre[4][128];    // raw Whh.hid, f32

    const int tid  = threadIdx.x;
    const int wave = tid >> 6;
    const int lane = tid & 63;
    const int w    = wave & 3;

    const f32x4 ZERO4 = {0.f, 0.f, 0.f, 0.f};

    // ---- LDS init: buf[1] = { f16(x), 0, 0, 0 }   (step 0 reads parity 1)
    if (tid < 64)       buf[1][0][tid] = pack2(x0[2 * tid], x0[2 * tid + 1]);
    else if (tid < 256) ((u32*)buf[1])[tid] = 0u;
    __syncthreads();

    if (wave < 4) {
        // ============ IH waves: critical dot2 chain (VALU only) ==========
        const int rsh = w * 32 + (lane >> 1);   // owned row
        const int kh  = lane & 1;               // k-half (64 elems)

        u32 wih[4][32];
        float bsum[4];
        #pragma unroll
        for (int l = 0; l < 4; ++l) {
            const float* p = Wih + ((size_t)(l * 128 + rsh)) * 128 + kh * 64;
            #pragma unroll
            for (int j = 0; j < 32; ++j)
                wih[l][j] = pack2(p[2 * j], p[2 * j + 1]);
            bsum[l] = bih[l * 128 + rsh] + bhh[l * 128 + rsh];
        }
        BAR();   // matches HH prologue barrier

#define SLOT_IH(l, P, CURB, STORE, S) do {                                    \
        float pr = pre[l][rsh];                                               \
        const u32* _yb = (CURB) + kh * 32;                                    \
        uint4 h0 = *(const uint4*)(_yb + 0);                                  \
        uint4 h1 = *(const uint4*)(_yb + 4);                                  \
        uint4 h2 = *(const uint4*)(_yb + 8);                                  \
        uint4 h3 = *(const uint4*)(_yb + 12);                                 \
        uint4 h4 = *(const uint4*)(_yb + 16);                                 \
        uint4 h5 = *(const uint4*)(_yb + 20);                                 \
        uint4 h6 = *(const uint4*)(_yb + 24);                                 \
        uint4 h7 = *(const uint4*)(_yb + 28);                                 \
        const u32* _wd = wih[l];                                              \
        float va = kh ? 0.f : (pr + bsum[l]);                                 \
        float vb = 0.f, vc = 0.f, vd = 0.f;                                   \
        va = dot2(h0.x, _wd[0], va);  vb = dot2(h0.y, _wd[1], vb);            \
        vc = dot2(h0.z, _wd[2], vc);  vd = dot2(h0.w, _wd[3], vd);            \
        va = dot2(h1.x, _wd[4], va);  vb = dot2(h1.y, _wd[5], vb);            \
        vc = dot2(h1.z, _wd[6], vc);  vd = dot2(h1.w, _wd[7], vd);            \
        va = dot2(h2.x, _wd[8], va);  vb = dot2(h2.y, _wd[9], vb);            \
        vc = dot2(h2.z, _wd[10], vc); vd = dot2(h2.w, _wd[11], vd);           \
        va = dot2(h3.x, _wd[12], va); vb = dot2(h3.y, _wd[13], vb);           \
        vc = dot2(h3.z, _wd[14], vc); vd = dot2(h3.w, _wd[15], vd);           \
        va = dot2(h4.x, _wd[16], va); vb = dot2(h4.y, _wd[17], vb);           \
        vc = dot2(h4.z, _wd[18], vc); vd = dot2(h4.w, _wd[19], vd);           \
        va = dot2(h5.x, _wd[20], va); vb = dot2(h5.y, _wd[21], vb);           \
        vc = dot2(h5.z, _wd[22], vc); vd = dot2(h5.w, _wd[23], vd);           \
        va = dot2(h6.x, _wd[24], va); vb = dot2(h6.y, _wd[25], vb);           \
        vc = dot2(h6.z, _wd[26], vc); vd = dot2(h6.w, _wd[27], vd);           \
        va = dot2(h7.x, _wd[28], va); vb = dot2(h7.y, _wd[29], vb);           \
        vc = dot2(h7.z, _wd[30], vc); vd = dot2(h7.w, _wd[31], vd);           \
        float v = (va + vb) + (vc + vd);                                      \
        v += __shfl_xor(v, 1);                                                \
        float y = fmaxf(v, 0.f);                                              \
        float yo = __shfl_xor(y, 2);                                          \
        if ((lane & 3) == 0) {                                                \
            u32 pk = pack2(y, yo);                                            \
            buf[P][l][w * 16 + (lane >> 2)] = pk;                             \
            if (STORE)                                                        \
                enc[(size_t)(S) * 64 + w * 16 + (lane >> 2)] = pk;            \
        }                                                                     \
        BAR();                                                                \
    } while (0)

        for (int s = 0; s < T; s += 2) {
            SLOT_IH(0, 0, &buf[1][3][0], 0, s);
            SLOT_IH(1, 0, &buf[0][0][0], 0, s);
            SLOT_IH(2, 0, &buf[0][1][0], 0, s);
            SLOT_IH(3, 0, &buf[0][2][0], 1, s);
            SLOT_IH(0, 1, &buf[0][3][0], 0, s + 1);
            SLOT_IH(1, 1, &buf[1][0][0], 0, s + 1);
            SLOT_IH(2, 1, &buf[1][1][0], 0, s + 1);
            SLOT_IH(3, 1, &buf[1][2][0], 1, s + 1);
        }
#undef SLOT_IH
    } else {
        // ============ HH waves: shadow MFMA chain (matrix pipe) ==========
        const int m = lane & 15;    // A row-in-tile / D col
        const int g = lane >> 4;    // k-group / D row-quad

        f16x8 hhA[4][2][4];         // [layer][tile][ktile] resident Whh frags
        #pragma unroll
        for (int l = 0; l < 4; ++l)
            #pragma unroll
            for (int t = 0; t < 2; ++t) {
                const int row = w * 32 + t * 16 + m;
                #pragma unroll
                for (int kt = 0; kt < 4; ++kt) {
                    const float* p = Whh + ((size_t)(l * 128 + row)) * 128
                                         + kt * 32 + g * 8;
                    f16x8 v;
                    #pragma unroll
                    for (int e = 0; e < 8; ++e) v[e] = (f16)p[e];
                    hhA[l][t][kt] = v;
                }
            }

        f16x8 pfA[4], pfB[4];
        f32x4 pdA0, pdA1, pdB0, pdB1;

        // prologue: pre[0] = Whh_0 . x (raw); pending pdA (-> pre[1]) = 0;
        // prefetch pfA from buf[1][2] (zeros) for slot 0's MFMA (-> pre[2]).
        {
            const u32* sb = &buf[1][0][0];
            f16x8 j0 = *(const f16x8*)(sb + 0 * 16 + g * 4);
            f16x8 j1 = *(const f16x8*)(sb + 1 * 16 + g * 4);
            f16x8 j2 = *(const f16x8*)(sb + 2 * 16 + g * 4);
            f16x8 j3 = *(const f16x8*)(sb + 3 * 16 + g * 4);
            f32x4 t0 = MFMA(hhA[0][0][0], j0, ZERO4);
            t0 = MFMA(hhA[0][0][1], j1, t0);
            t0 = MFMA(hhA[0][0][2], j2, t0);
            t0 = MFMA(hhA[0][0][3], j3, t0);
            f32x4 t1 = MFMA(hhA[0][1][0], j0, ZERO4);
            t1 = MFMA(hhA[0][1][1], j1, t1);
            t1 = MFMA(hhA[0][1][2], j2, t1);
            t1 = MFMA(hhA[0][1][3], j3, t1);
            if (m == 0) {
                *(f32x4*)&pre[0][w * 32 + g * 4] = t0;
                *(f32x4*)&pre[0][w * 32 + 16 + g * 4] = t1;
            }
            pdA0 = ZERO4;
            pdA1 = ZERO4;
            const u32* pb = &buf[1][2][0];
            #pragma unroll
            for (int kt = 0; kt < 4; ++kt)
                pfA[kt] = *(const f16x8*)(pb + kt * 16 + g * 4);
        }
        BAR();   // matches IH post-weight-load barrier

        // slot: write pending -> pre[LW]; MFMA layer LC on PF_USE -> new
        // pending; prefetch PF_NEW from CURB (same buffer IH reads now).
#define SLOT_HH(LW, LC, PDW0, PDW1, PDN0, PDN1, PF_USE, PF_NEW, CURB) do {    \
        if (m == 0) {                                                         \
            *(f32x4*)&pre[LW][w * 32 + g * 4] = PDW0;                         \
            *(f32x4*)&pre[LW][w * 32 + 16 + g * 4] = PDW1;                    \
        }                                                                     \
        PDN0 = MFMA(hhA[LC][0][0], PF_USE[0], ZERO4);                         \
        PDN0 = MFMA(hhA[LC][0][1], PF_USE[1], PDN0);                          \
        PDN0 = MFMA(hhA[LC][0][2], PF_USE[2], PDN0);                          \
        PDN0 = MFMA(hhA[LC][0][3], PF_USE[3], PDN0);                          \
        PDN1 = MFMA(hhA[LC][1][0], PF_USE[0], ZERO4);                         \
        PDN1 = MFMA(hhA[LC][1][1], PF_USE[1], PDN1);                          \
        PDN1 = MFMA(hhA[LC][1][2], PF_USE[2], PDN1);                          \
        PDN1 = MFMA(hhA[LC][1][3], PF_USE[3], PDN1);                          \
        const u32* _pb = (CURB);                                              \
        PF_NEW[0] = *(const f16x8*)(_pb + 0 * 16 + g * 4);                    \
        PF_NEW[1] = *(const f16x8*)(_pb + 1 * 16 + g * 4);                    \
        PF_NEW[2] = *(const f16x8*)(_pb + 2 * 16 + g * 4);                    \
        PF_NEW[3] = *(const f16x8*)(_pb + 3 * 16 + g * 4);                    \
        BAR();                                                                \
    } while (0)

        for (int s = 0; s < T; s += 2) {
            SLOT_HH(1, 2, pdA0, pdA1, pdB0, pdB1, pfA, pfB, &buf[1][3][0]);
            SLOT_HH(2, 3, pdB0, pdB1, pdA0, pdA1, pfB, pfA, &buf[0][0][0]);
            SLOT_HH(3, 0, pdA0, pdA1, pdB0, pdB1, pfA, pfB, &buf[0][1][0]);
            SLOT_HH(0, 1, pdB0, pdB1, pdA0, pdA1, pfB, pfA, &buf[0][2][0]);
            SLOT_HH(1, 2, pdA0, pdA1, pdB0, pdB1, pfA, pfB, &buf[0][3][0]);
            SLOT_HH(2, 3, pdB0, pdB1, pdA0, pdA1, pfB, pfA, &buf[1][0][0]);
            SLOT_HH(3, 0, pdA0, pdA1, pdB0, pdB1, pfA, pfB, &buf[1][1][0]);
            SLOT_HH(0, 1, pdB0, pdB1, pdA0, pdA1, pfB, pfA, &buf[1][2][0]);
        }
#undef SLOT_HH
    }

    __syncthreads();
    if (tid == 0)
        __hip_atomic_store(flag, 1u, __ATOMIC_RELEASE, __HIP_MEMORY_SCOPE_AGENT);
}

// ---------------------------------------------------------------------------
// Heads kernel: grid (3 heads, T/32 row-segments), 256 threads. (unchanged)
// ---------------------------------------------------------------------------
__global__ __launch_bounds__(256) void heads_kernel(
    const u32* __restrict__ enc,
    const float* __restrict__ arw, const float* __restrict__ arb,
    const float* __restrict__ aw,  const float* __restrict__ ab,
    const float* __restrict__ prw, const float* __restrict__ prb,
    const float* __restrict__ pw,  const float* __restrict__ pb,
    const float* __restrict__ mrw, const float* __restrict__ mrb,
    const float* __restrict__ mw,  const float* __restrict__ mb,
    float* __restrict__ out, int T)
{
    const int head = blockIdx.x;
    const int r0 = blockIdx.y * 32;
    if (r0 >= T) return;

    const float *rbw, *rbb, *ow, *ob;
    int od, oc;
    if (head == 0)      { rbw = arw; rbb = arb; ow = aw; ob = ab; od = 8; oc = 0; }
    else if (head == 1) { rbw = prw; rbb = prb; ow = pw; ob = pb; od = 1; oc = 8; }
    else                { rbw = mrw; rbb = mrb; ow = mw; ob = mb; od = 1; oc = 9; }

    __shared__ u32 xs[32][64];
    __shared__ u32 hs[32][64];

    const int tid = threadIdx.x;

    #pragma unroll
    for (int rep = 0; rep < 8; ++rep) {
        int u = tid + rep * 256;
        int row = u >> 6, p = u & 63;
        xs[row][p] = enc[(size_t)(r0 + row) * 64 + p];
    }
    __syncthreads();

    const int j = tid & 127;
    const int rh = tid >> 7;

    float acc[16];
    u32 wreg[64];

#define PACKW(WPTR) do {                                                    \
        const float* _w = (WPTR);                                           \
        _Pragma("unroll")                                                   \
        for (int cc = 0; cc < 16; ++cc) {                                   \
            float4 aa = *(const float4*)(_w + cc * 8);                      \
            float4 bb = *(const float4*)(_w + cc * 8 + 4);                  \
            wreg[cc * 4 + 0] = pack2(aa.x, aa.y);                           \
            wreg[cc * 4 + 1] = pack2(aa.z, aa.w);                           \
            wreg[cc * 4 + 2] = pack2(bb.x, bb.y);                           \
            wreg[cc * 4 + 3] = pack2(bb.z, bb.w);                           \
        }                                                                   \
    } while (0)

#define MM16(SRC) do {                                                      \
        _Pragma("unroll")                                                   \
        for (int r = 0; r < 16; ++r) acc[r] = 0.f;                          \
        _Pragma("unroll")                                                   \
        for (int kp = 0; kp < 16; ++kp) {                                   \
            u32 w0 = wreg[kp * 4 + 0], w1 = wreg[kp * 4 + 1];               \
            u32 w2 = wreg[kp * 4 + 2], w3 = wreg[kp * 4 + 3];               \
            _Pragma("unroll")                                               \
            for (int r = 0; r < 16; ++r) {                                  \
                uint4 x4 = *(const uint4*)(&SRC[rh * 16 + r][kp * 4]);      \
                acc[r] = dot2(x4.x, w0, acc[r]);                            \
                acc[r] = dot2(x4.y, w1, acc[r]);                            \
                acc[r] = dot2(x4.z, w2, acc[r]);                            \
                acc[r] = dot2(x4.w, w3, acc[r]);                            \
            }                                                               \
        }                                                                   \
    } while (0)

    #pragma unroll
    for (int blk = 0; blk < 2; ++blk) {
        PACKW(rbw + (size_t)((blk * 2 + 0) * 128 + j) * 128);
        MM16(xs);
        {
            float b1 = rbb[(blk * 2 + 0) * 128 + j];
            #pragma unroll
            for (int r = 0; r < 16; ++r) {
                float v = acc[r] + b1;
                v = fmaxf(v, 0.2f * v);
                reinterpret_cast<unsigned short*>(&hs[rh * 16 + r][0])[j] = f16bits(v);
            }
        }
        __syncthreads();

        PACKW(rbw + (size_t)((blk * 2 + 1) * 128 + j) * 128);
        MM16(hs);
        {
            float b2 = rbb[(blk * 2 + 1) * 128 + j];
            #pragma unroll
            for (int r = 0; r < 16; ++r) {
                int row = rh * 16 + r;
                unsigned short xb =
                    reinterpret_cast<const unsigned short*>(&xs[row][0])[j];
                float xold = (float)__builtin_bit_cast(f16, xb);
                float v = xold + acc[r] + b2;
                v = fmaxf(v, 0.2f * v);
                reinterpret_cast<unsigned short*>(&xs[row][0])[j] = f16bits(v);
            }
        }
        __syncthreads();
    }

    {
        const int o = tid & 15;
        const int rr = tid >> 4;
        if (o < od) {
            PACKW(ow + (size_t)o * 128);
            float obv = ob[o];
            #pragma unroll
            for (int rs = 0; rs < 2; ++rs) {
                const int row = rr * 2 + rs;
                float a = 0.f;
                #pragma unroll
                for (int kp = 0; kp < 64; ++kp) a = dot2(xs[row][kp], wreg[kp], a);
                out[(size_t)(r0 + row) * 10 + oc + o] = a + obv;
            }
        }
    }
#undef PACKW
#undef MM16
}

extern "C" void kernel_launch(void* const* d_in, const int* in_sizes, int n_in,
                              void* d_out, int out_size, void* d_ws, size_t ws_size,
                              hipStream_t stream)
{
    const float* x   = (const float*)d_in[0];
    const float* Wih = (const float*)d_in[1];
    const float* Whh = (const float*)d_in[2];
    const float* bih = (const float*)d_in[3];
    const float* bhh = (const float*)d_in[4];
    const float* arw = (const float*)d_in[5];
    const float* arb = (const float*)d_in[6];
    const float* aw  = (const float*)d_in[7];
    const float* ab  = (const float*)d_in[8];
    const float* prw = (const float*)d_in[9];
    const float* prb = (const float*)d_in[10];
    const float* pw  = (const float*)d_in[11];
    const float* pb  = (const float*)d_in[12];
    const float* mrw = (const float*)d_in[13];
    const float* mrb = (const float*)d_in[14];
    const float* mw  = (const float*)d_in[15];
    const float* mb  = (const float*)d_in[16];

    const int T = out_size / 10;             // 32768
    u32* enc  = (u32*)d_ws;                  // T*64 u32 (f16 pairs) = 8 MB
    u32* flag = enc + (size_t)T * 64;        // done-flag for heater blocks

    reset_flag<<<1, 1, 0, stream>>>(flag);

    rnn_kernel<<<256, 512, 0, stream>>>(x, Wih, Whh, bih, bhh, enc, flag, T);

    heads_kernel<<<dim3(3, (T + 31) / 32), 256, 0, stream>>>(
        enc, arw, arb, aw, ab, prw, prb, pw, pb, mrw, mrb, mw, mb,
        (float*)d_out, T);
}

// Round 9
// 38027.069 us; speedup vs baseline: 1.4138x; 1.0752x over previous
//
#include <hip/hip_runtime.h>
#include <cstdint>

typedef uint32_t u32;
typedef _Float16 f16;
typedef f16 f16x2 __attribute__((ext_vector_type(2)));
typedef f16 f16x8 __attribute__((ext_vector_type(8)));
typedef float f32x4 __attribute__((ext_vector_type(4)));

static __device__ __forceinline__ u32 pack2(float a, float b) {
    f16x2 v;
    v.x = (f16)a;
    v.y = (f16)b;
    return __builtin_bit_cast(u32, v);
}

static __device__ __forceinline__ float dot2(u32 a, u32 b, float c) {
    return __builtin_amdgcn_fdot2(__builtin_bit_cast(f16x2, a),
                                  __builtin_bit_cast(f16x2, b), c, false);
}

static __device__ __forceinline__ unsigned short f16bits(float v) {
    return __builtin_bit_cast(unsigned short, (f16)v);
}

// barrier without vmcnt(0) drain (global enc stores must not stall the loop)
#define BAR() asm volatile("s_waitcnt lgkmcnt(0)\n\ts_barrier" ::: "memory")

#define MFMA(A, B, C) __builtin_amdgcn_mfma_f32_16x16x32_f16(A, B, C, 0, 0, 0)

// ---------------------------------------------------------------------------
// RNN kernel: 1 workgroup, 512 threads (8 waves = 2/SIMD), persistent.
// R6's wave-specialization skeleton with the pipes SWAPPED (R8 structure,
// heater removed — R8 profiling showed the structure is fine; the heater's
// atomic-poll storm + power draw caused the regression):
//  - waves 0-3 (IH, critical, VALU dot2): y_l = relu(Wih_l.cur + pre[l] + b).
//    Lane: row = w*32+(lane>>1), kh = lane&1. 8 ds_read_b128 + 32 dot2 +
//    1 DPP reduce + single ds_write_b16 (no pack-exchange on the tail).
//  - waves 4-7 (HH, shadow, MFMA pipe): pre[(l+1)&3] written from pending D
//    regs; 8 MFMAs (C=0) for (l+2)&3 on B-frags PREFETCHED one slot early
//    (ping-pong pfA/pfB) so HH LDS reads are off-critical; prefetch for
//    (l+3)&3 from the same buffer IH reads this slot.
// LDS ops/slot: 48 vs R6's 64 (the CU LDS pipe was the R6 wall), and HH
// waves reach the barrier early (less straggler skew).
// State f16 in LDS buf[2][4][64]; pre[4][128] f32 raw. 1 lgkm barrier/slot.
// ---------------------------------------------------------------------------
__global__ __launch_bounds__(512, 2) void rnn_kernel(
    const float* __restrict__ x0,
    const float* __restrict__ Wih, const float* __restrict__ Whh,
    const float* __restrict__ bih, const float* __restrict__ bhh,
    u32* __restrict__ enc, int T)
{
    __shared__ u32 buf[2][4][64];    // per-layer outputs, f16 pairs
    __shared__ float pre[4][128];    // raw Whh.hid, f32

    const int tid  = threadIdx.x;
    const int wave = tid >> 6;
    const int lane = tid & 63;
    const int w    = wave & 3;

    const f32x4 ZERO4 = {0.f, 0.f, 0.f, 0.f};

    // ---- LDS init: buf[1] = { f16(x), 0, 0, 0 }   (step 0 reads parity 1)
    if (tid < 64)       buf[1][0][tid] = pack2(x0[2 * tid], x0[2 * tid + 1]);
    else if (tid < 256) ((u32*)buf[1])[tid] = 0u;
    __syncthreads();

    if (wave < 4) {
        // ============ IH waves: critical dot2 chain (VALU only) ==========
        const int rsh = w * 32 + (lane >> 1);   // owned row
        const int kh  = lane & 1;               // k-half (64 elems)

        u32 wih[4][32];
        float bsum[4];
        #pragma unroll
        for (int l = 0; l < 4; ++l) {
            const float* p = Wih + ((size_t)(l * 128 + rsh)) * 128 + kh * 64;
            #pragma unroll
            for (int j = 0; j < 32; ++j)
                wih[l][j] = pack2(p[2 * j], p[2 * j + 1]);
            bsum[l] = bih[l * 128 + rsh] + bhh[l * 128 + rsh];
        }
        BAR();   // matches HH prologue barrier

#define SLOT_IH(l, P, CURB, STORE, S) do {                                    \
        float pr = pre[l][rsh];                                               \
        const u32* _yb = (CURB) + kh * 32;                                    \
        uint4 h0 = *(const uint4*)(_yb + 0);                                  \
        uint4 h1 = *(const uint4*)(_yb + 4);                                  \
        uint4 h2 = *(const uint4*)(_yb + 8);                                  \
        uint4 h3 = *(const uint4*)(_yb + 12);                                 \
        uint4 h4 = *(const uint4*)(_yb + 16);                                 \
        uint4 h5 = *(const uint4*)(_yb + 20);                                 \
        uint4 h6 = *(const uint4*)(_yb + 24);                                 \
        uint4 h7 = *(const uint4*)(_yb + 28);                                 \
        const u32* _wd = wih[l];                                              \
        float va = kh ? 0.f : (pr + bsum[l]);                                 \
        float vb = 0.f, vc = 0.f, vd = 0.f;                                   \
        va = dot2(h0.x, _wd[0], va);  vb = dot2(h0.y, _wd[1], vb);            \
        vc = dot2(h0.z, _wd[2], vc);  vd = dot2(h0.w, _wd[3], vd);            \
        va = dot2(h1.x, _wd[4], va);  vb = dot2(h1.y, _wd[5], vb);            \
        vc = dot2(h1.z, _wd[6], vc);  vd = dot2(h1.w, _wd[7], vd);            \
        va = dot2(h2.x, _wd[8], va);  vb = dot2(h2.y, _wd[9], vb);            \
        vc = dot2(h2.z, _wd[10], vc); vd = dot2(h2.w, _wd[11], vd);           \
        va = dot2(h3.x, _wd[12], va); vb = dot2(h3.y, _wd[13], vb);           \
        vc = dot2(h3.z, _wd[14], vc); vd = dot2(h3.w, _wd[15], vd);           \
        va = dot2(h4.x, _wd[16], va); vb = dot2(h4.y, _wd[17], vb);           \
        vc = dot2(h4.z, _wd[18], vc); vd = dot2(h4.w, _wd[19], vd);           \
        va = dot2(h5.x, _wd[20], va); vb = dot2(h5.y, _wd[21], vb);           \
        vc = dot2(h5.z, _wd[22], vc); vd = dot2(h5.w, _wd[23], vd);           \
        va = dot2(h6.x, _wd[24], va); vb = dot2(h6.y, _wd[25], vb);           \
        vc = dot2(h6.z, _wd[26], vc); vd = dot2(h6.w, _wd[27], vd);           \
        va = dot2(h7.x, _wd[28], va); vb = dot2(h7.y, _wd[29], vb);           \
        vc = dot2(h7.z, _wd[30], vc); vd = dot2(h7.w, _wd[31], vd);           \
        float v = (va + vb) + (vc + vd);                                      \
        v += __shfl_xor(v, 1);                                                \
        float y = fmaxf(v, 0.f);                                              \
        if (kh == 0) {                                                        \
            unsigned short yb16 = f16bits(y);                                 \
            ((unsigned short*)&buf[P][l][0])[rsh] = yb16;                     \
            if (STORE)                                                        \
                ((unsigned short*)enc)[(size_t)(S) * 128 + rsh] = yb16;       \
        }                                                                     \
        BAR();                                                                \
    } while (0)

        for (int s = 0; s < T; s += 2) {
            SLOT_IH(0, 0, &buf[1][3][0], 0, s);
            SLOT_IH(1, 0, &buf[0][0][0], 0, s);
            SLOT_IH(2, 0, &buf[0][1][0], 0, s);
            SLOT_IH(3, 0, &buf[0][2][0], 1, s);
            SLOT_IH(0, 1, &buf[0][3][0], 0, s + 1);
            SLOT_IH(1, 1, &buf[1][0][0], 0, s + 1);
            SLOT_IH(2, 1, &buf[1][1][0], 0, s + 1);
            SLOT_IH(3, 1, &buf[1][2][0], 1, s + 1);
        }
#undef SLOT_IH
    } else {
        // ============ HH waves: shadow MFMA chain (matrix pipe) ==========
        const int m = lane & 15;    // A row-in-tile / D col
        const int g = lane >> 4;    // k-group / D row-quad

        f16x8 hhA[4][2][4];         // [layer][tile][ktile] resident Whh frags
        #pragma unroll
        for (int l = 0; l < 4; ++l)
            #pragma unroll
            for (int t = 0; t < 2; ++t) {
                const int row = w * 32 + t * 16 + m;
                #pragma unroll
                for (int kt = 0; kt < 4; ++kt) {
                    const float* p = Whh + ((size_t)(l * 128 + row)) * 128
                                         + kt * 32 + g * 8;
                    f16x8 v;
                    #pragma unroll
                    for (int e = 0; e < 8; ++e) v[e] = (f16)p[e];
                    hhA[l][t][kt] = v;
                }
            }

        f16x8 pfA[4], pfB[4];
        f32x4 pdA0, pdA1, pdB0, pdB1;

        // prologue: pre[0] = Whh_0 . x (raw); pending pdA (-> pre[1]) = 0;
        // prefetch pfA from buf[1][2] (zeros) for slot 0's MFMA (-> pre[2]).
        {
            const u32* sb = &buf[1][0][0];
            f16x8 j0 = *(const f16x8*)(sb + 0 * 16 + g * 4);
            f16x8 j1 = *(const f16x8*)(sb + 1 * 16 + g * 4);
            f16x8 j2 = *(const f16x8*)(sb + 2 * 16 + g * 4);
            f16x8 j3 = *(const f16x8*)(sb + 3 * 16 + g * 4);
            f32x4 t0 = MFMA(hhA[0][0][0], j0, ZERO4);
            t0 = MFMA(hhA[0][0][1], j1, t0);
            t0 = MFMA(hhA[0][0][2], j2, t0);
            t0 = MFMA(hhA[0][0][3], j3, t0);
            f32x4 t1 = MFMA(hhA[0][1][0], j0, ZERO4);
            t1 = MFMA(hhA[0][1][1], j1, t1);
            t1 = MFMA(hhA[0][1][2], j2, t1);
            t1 = MFMA(hhA[0][1][3], j3, t1);
            if (m == 0) {
                *(f32x4*)&pre[0][w * 32 + g * 4] = t0;
                *(f32x4*)&pre[0][w * 32 + 16 + g * 4] = t1;
            }
            pdA0 = ZERO4;
            pdA1 = ZERO4;
            const u32* pb = &buf[1][2][0];
            #pragma unroll
            for (int kt = 0; kt < 4; ++kt)
                pfA[kt] = *(const f16x8*)(pb + kt * 16 + g * 4);
        }
        BAR();   // matches IH post-weight-load barrier

        // slot: write pending -> pre[LW]; MFMA layer LC on PF_USE -> new
        // pending; prefetch PF_NEW from CURB (same buffer IH reads now).
#define SLOT_HH(LW, LC, PDW0, PDW1, PDN0, PDN1, PF_USE, PF_NEW, CURB) do {    \
        if (m == 0) {                                                         \
            *(f32x4*)&pre[LW][w * 32 + g * 4] = PDW0;                         \
            *(f32x4*)&pre[LW][w * 32 + 16 + g * 4] = PDW1;                    \
        }                                                                     \
        PDN0 = MFMA(hhA[LC][0][0], PF_USE[0], ZERO4);                         \
        PDN0 = MFMA(hhA[LC][0][1], PF_USE[1], PDN0);                          \
        PDN0 = MFMA(hhA[LC][0][2], PF_USE[2], PDN0);                          \
        PDN0 = MFMA(hhA[LC][0][3], PF_USE[3], PDN0);                          \
        PDN1 = MFMA(hhA[LC][1][0], PF_USE[0], ZERO4);                         \
        PDN1 = MFMA(hhA[LC][1][1], PF_USE[1], PDN1);                          \
        PDN1 = MFMA(hhA[LC][1][2], PF_USE[2], PDN1);                          \
        PDN1 = MFMA(hhA[LC][1][3], PF_USE[3], PDN1);                          \
        const u32* _pb = (CURB);                                              \
        PF_NEW[0] = *(const f16x8*)(_pb + 0 * 16 + g * 4);                    \
        PF_NEW[1] = *(const f16x8*)(_pb + 1 * 16 + g * 4);                    \
        PF_NEW[2] = *(const f16x8*)(_pb + 2 * 16 + g * 4);                    \
        PF_NEW[3] = *(const f16x8*)(_pb + 3 * 16 + g * 4);                    \
        BAR();                                                                \
    } while (0)

        for (int s = 0; s < T; s += 2) {
            SLOT_HH(1, 2, pdA0, pdA1, pdB0, pdB1, pfA, pfB, &buf[1][3][0]);
            SLOT_HH(2, 3, pdB0, pdB1, pdA0, pdA1, pfB, pfA, &buf[0][0][0]);
            SLOT_HH(3, 0, pdA0, pdA1, pdB0, pdB1, pfA, pfB, &buf[0][1][0]);
            SLOT_HH(0, 1, pdB0, pdB1, pdA0, pdA1, pfB, pfA, &buf[0][2][0]);
            SLOT_HH(1, 2, pdA0, pdA1, pdB0, pdB1, pfA, pfB, &buf[0][3][0]);
            SLOT_HH(2, 3, pdB0, pdB1, pdA0, pdA1, pfB, pfA, &buf[1][0][0]);
            SLOT_HH(3, 0, pdA0, pdA1, pdB0, pdB1, pfA, pfB, &buf[1][1][0]);
            SLOT_HH(0, 1, pdB0, pdB1, pdA0, pdA1, pfB, pfA, &buf[1][2][0]);
        }
#undef SLOT_HH
    }
}

// ---------------------------------------------------------------------------
// Heads kernel: grid (3 heads, T/32 row-segments), 256 threads. (unchanged)
// ---------------------------------------------------------------------------
__global__ __launch_bounds__(256) void heads_kernel(
    const u32* __restrict__ enc,
    const float* __restrict__ arw, const float* __restrict__ arb,
    const float* __restrict__ aw,  const float* __restrict__ ab,
    const float* __restrict__ prw, const float* __restrict__ prb,
    const float* __restrict__ pw,  const float* __restrict__ pb,
    const float* __restrict__ mrw, const float* __restrict__ mrb,
    const float* __restrict__ mw,  const float* __restrict__ mb,
    float* __restrict__ out, int T)
{
    const int head = blockIdx.x;
    const int r0 = blockIdx.y * 32;
    if (r0 >= T) return;

    const float *rbw, *rbb, *ow, *ob;
    int od, oc;
    if (head == 0)      { rbw = arw; rbb = arb; ow = aw; ob = ab; od = 8; oc = 0; }
    else if (head == 1) { rbw = prw; rbb = prb; ow = pw; ob = pb; od = 1; oc = 8; }
    else                { rbw = mrw; rbb = mrb; ow = mw; ob = mb; od = 1; oc = 9; }

    __shared__ u32 xs[32][64];
    __shared__ u32 hs[32][64];

    const int tid = threadIdx.x;

    #pragma unroll
    for (int rep = 0; rep < 8; ++rep) {
        int u = tid + rep * 256;
        int row = u >> 6, p = u & 63;
        xs[row][p] = enc[(size_t)(r0 + row) * 64 + p];
    }
    __syncthreads();

    const int j = tid & 127;
    const int rh = tid >> 7;

    float acc[16];
    u32 wreg[64];

#define PACKW(WPTR) do {                                                    \
        const float* _w = (WPTR);                                           \
        _Pragma("unroll")                                                   \
        for (int cc = 0; cc < 16; ++cc) {                                   \
            float4 aa = *(const float4*)(_w + cc * 8);                      \
            float4 bb = *(const float4*)(_w + cc * 8 + 4);                  \
            wreg[cc * 4 + 0] = pack2(aa.x, aa.y);                           \
            wreg[cc * 4 + 1] = pack2(aa.z, aa.w);                           \
            wreg[cc * 4 + 2] = pack2(bb.x, bb.y);                           \
            wreg[cc * 4 + 3] = pack2(bb.z, bb.w);                           \
        }                                                                   \
    } while (0)

#define MM16(SRC) do {                                                      \
        _Pragma("unroll")                                                   \
        for (int r = 0; r < 16; ++r) acc[r] = 0.f;                          \
        _Pragma("unroll")                                                   \
        for (int kp = 0; kp < 16; ++kp) {                                   \
            u32 w0 = wreg[kp * 4 + 0], w1 = wreg[kp * 4 + 1];               \
            u32 w2 = wreg[kp * 4 + 2], w3 = wreg[kp * 4 + 3];               \
            _Pragma("unroll")                                               \
            for (int r = 0; r < 16; ++r) {                                  \
                uint4 x4 = *(const uint4*)(&SRC[rh * 16 + r][kp * 4]);      \
                acc[r] = dot2(x4.x, w0, acc[r]);                            \
                acc[r] = dot2(x4.y, w1, acc[r]);                            \
                acc[r] = dot2(x4.z, w2, acc[r]);                            \
                acc[r] = dot2(x4.w, w3, acc[r]);                            \
            }                                                               \
        }                                                                   \
    } while (0)

    #pragma unroll
    for (int blk = 0; blk < 2; ++blk) {
        PACKW(rbw + (size_t)((blk * 2 + 0) * 128 + j) * 128);
        MM16(xs);
        {
            float b1 = rbb[(blk * 2 + 0) * 128 + j];
            #pragma unroll
            for (int r = 0; r < 16; ++r) {
                float v = acc[r] + b1;
                v = fmaxf(v, 0.2f * v);
                reinterpret_cast<unsigned short*>(&hs[rh * 16 + r][0])[j] = f16bits(v);
            }
        }
        __syncthreads();

        PACKW(rbw + (size_t)((blk * 2 + 1) * 128 + j) * 128);
        MM16(hs);
        {
            float b2 = rbb[(blk * 2 + 1) * 128 + j];
            #pragma unroll
            for (int r = 0; r < 16; ++r) {
                int row = rh * 16 + r;
                unsigned short xb =
                    reinterpret_cast<const unsigned short*>(&xs[row][0])[j];
                float xold = (float)__builtin_bit_cast(f16, xb);
                float v = xold + acc[r] + b2;
                v = fmaxf(v, 0.2f * v);
                reinterpret_cast<unsigned short*>(&xs[row][0])[j] = f16bits(v);
            }
        }
        __syncthreads();
    }

    {
        const int o = tid & 15;
        const int rr = tid >> 4;
        if (o < od) {
            PACKW(ow + (size_t)o * 128);
            float obv = ob[o];
            #pragma unroll
            for (int rs = 0; rs < 2; ++rs) {
                const int row = rr * 2 + rs;
                float a = 0.f;
                #pragma unroll
                for (int kp = 0; kp < 64; ++kp) a = dot2(xs[row][kp], wreg[kp], a);
                out[(size_t)(r0 + row) * 10 + oc + o] = a + obv;
            }
        }
    }
#undef PACKW
#undef MM16
}

extern "C" void kernel_launch(void* const* d_in, const int* in_sizes, int n_in,
                              void* d_out, int out_size, void* d_ws, size_t ws_size,
                              hipStream_t stream)
{
    const float* x   = (const float*)d_in[0];
    const float* Wih = (const float*)d_in[1];
    const float* Whh = (const float*)d_in[2];
    const float* bih = (const float*)d_in[3];
    const float* bhh = (const float*)d_in[4];
    const float* arw = (const float*)d_in[5];
    const float* arb = (const float*)d_in[6];
    const float* aw  = (const float*)d_in[7];
    const float* ab  = (const float*)d_in[8];
    const float* prw = (const float*)d_in[9];
    const float* prb = (const float*)d_in[10];
    const float* pw  = (const float*)d_in[11];
    const float* pb  = (const float*)d_in[12];
    const float* mrw = (const float*)d_in[13];
    const float* mrb = (const float*)d_in[14];
    const float* mw  = (const float*)d_in[15];
    const float* mb  = (const float*)d_in[16];

    const int T = out_size / 10;             // 32768
    u32* enc = (u32*)d_ws;                   // T*64 u32 (f16 pairs) = 8 MB

    rnn_kernel<<<1, 512, 0, stream>>>(x, Wih, Whh, bih, bhh, enc, T);

    heads_kernel<<<dim3(3, (T + 31) / 32), 256, 0, stream>>>(
        enc, arw, arb, aw, ab, prw, prb, pw, pb, mrw, mrb, mw, mb,
        (float*)d_out, T);
}

// Round 10
// 35465.262 us; speedup vs baseline: 1.5159x; 1.0722x over previous
//
#include <hip/hip_runtime.h>
#include <cstdint>

typedef uint32_t u32;
typedef _Float16 f16;
typedef f16 f16x2 __attribute__((ext_vector_type(2)));
typedef f16 f16x8 __attribute__((ext_vector_type(8)));
typedef float f32x4 __attribute__((ext_vector_type(4)));

static __device__ __forceinline__ u32 pack2(float a, float b) {
    f16x2 v;
    v.x = (f16)a;
    v.y = (f16)b;
    return __builtin_bit_cast(u32, v);
}

static __device__ __forceinline__ float dot2(u32 a, u32 b, float c) {
    return __builtin_amdgcn_fdot2(__builtin_bit_cast(f16x2, a),
                                  __builtin_bit_cast(f16x2, b), c, false);
}

static __device__ __forceinline__ unsigned short f16bits(float v) {
    return __builtin_bit_cast(unsigned short, (f16)v);
}

// xor-1 pair reduce via DPP quad_perm [1,0,3,2] (ALU-speed; __shfl_xor would
// lower to ds_swizzle_b32 = LDS pipe, ~100cy on the critical chain)
static __device__ __forceinline__ float dpp_xor1_add(float v) {
    int x = __builtin_amdgcn_update_dpp(0, __builtin_bit_cast(int, v),
                                        0xB1, 0xF, 0xF, true);
    return v + __builtin_bit_cast(float, x);
}

// barrier without vmcnt(0) drain (global enc stores must not stall the loop)
#define BAR() asm volatile("s_waitcnt lgkmcnt(0)\n\ts_barrier" ::: "memory")

#define MFMA(A, B, C) __builtin_amdgcn_mfma_f32_16x16x32_f16(A, B, C, 0, 0, 0)

// ---------------------------------------------------------------------------
// RNN kernel: 1 workgroup, 512 threads (8 waves = 2/SIMD), persistent.
// Wave-specialized (R6 skeleton), pipes per R9, DPP reduce (R10):
//  - waves 0-3 (IH, critical, VALU dot2): y_l = relu(Wih_l.cur + pre[l] + b).
//    Lane: row = w*32+(lane>>1), kh = lane&1. 8 ds_read_b128 + 32 dot2 +
//    DPP pair-reduce + single ds_write_b16.
//  - waves 4-7 (HH, shadow, MFMA pipe): pre[(l+1)&3] written from pending D
//    regs; 8 MFMAs (C=0) for (l+2)&3 on B-frags PREFETCHED one slot early
//    (ping-pong pfA/pfB); prefetch for (l+3)&3 from the buffer IH reads now.
// State f16 in LDS buf[2][4][64]; pre[4][128] f32 raw. 1 lgkm barrier/slot.
// ---------------------------------------------------------------------------
__global__ __launch_bounds__(512, 2) void rnn_kernel(
    const float* __restrict__ x0,
    const float* __restrict__ Wih, const float* __restrict__ Whh,
    const float* __restrict__ bih, const float* __restrict__ bhh,
    u32* __restrict__ enc, int T)
{
    __shared__ u32 buf[2][4][64];    // per-layer outputs, f16 pairs
    __shared__ float pre[4][128];    // raw Whh.hid, f32

    const int tid  = threadIdx.x;
    const int wave = tid >> 6;
    const int lane = tid & 63;
    const int w    = wave & 3;

    const f32x4 ZERO4 = {0.f, 0.f, 0.f, 0.f};

    // ---- LDS init: buf[1] = { f16(x), 0, 0, 0 }   (step 0 reads parity 1)
    if (tid < 64)       buf[1][0][tid] = pack2(x0[2 * tid], x0[2 * tid + 1]);
    else if (tid < 256) ((u32*)buf[1])[tid] = 0u;
    __syncthreads();

    if (wave < 4) {
        // ============ IH waves: critical dot2 chain (VALU only) ==========
        const int rsh = w * 32 + (lane >> 1);   // owned row
        const int kh  = lane & 1;               // k-half (64 elems)

        u32 wih[4][32];
        float bsum[4];
        #pragma unroll
        for (int l = 0; l < 4; ++l) {
            const float* p = Wih + ((size_t)(l * 128 + rsh)) * 128 + kh * 64;
            #pragma unroll
            for (int j = 0; j < 32; ++j)
                wih[l][j] = pack2(p[2 * j], p[2 * j + 1]);
            bsum[l] = bih[l * 128 + rsh] + bhh[l * 128 + rsh];
        }
        BAR();   // matches HH prologue barrier

#define SLOT_IH(l, P, CURB, STORE, S) do {                                    \
        float pr = pre[l][rsh];                                               \
        const u32* _yb = (CURB) + kh * 32;                                    \
        uint4 h0 = *(const uint4*)(_yb + 0);                                  \
        uint4 h1 = *(const uint4*)(_yb + 4);                                  \
        uint4 h2 = *(const uint4*)(_yb + 8);                                  \
        uint4 h3 = *(const uint4*)(_yb + 12);                                 \
        uint4 h4 = *(const uint4*)(_yb + 16);                                 \
        uint4 h5 = *(const uint4*)(_yb + 20);                                 \
        uint4 h6 = *(const uint4*)(_yb + 24);                                 \
        uint4 h7 = *(const uint4*)(_yb + 28);                                 \
        const u32* _wd = wih[l];                                              \
        float va = kh ? 0.f : (pr + bsum[l]);                                 \
        float vb = 0.f, vc = 0.f, vd = 0.f;                                   \
        va = dot2(h0.x, _wd[0], va);  vb = dot2(h0.y, _wd[1], vb);            \
        vc = dot2(h0.z, _wd[2], vc);  vd = dot2(h0.w, _wd[3], vd);            \
        va = dot2(h1.x, _wd[4], va);  vb = dot2(h1.y, _wd[5], vb);            \
        vc = dot2(h1.z, _wd[6], vc);  vd = dot2(h1.w, _wd[7], vd);            \
        va = dot2(h2.x, _wd[8], va);  vb = dot2(h2.y, _wd[9], vb);            \
        vc = dot2(h2.z, _wd[10], vc); vd = dot2(h2.w, _wd[11], vd);           \
        va = dot2(h3.x, _wd[12], va); vb = dot2(h3.y, _wd[13], vb);           \
        vc = dot2(h3.z, _wd[14], vc); vd = dot2(h3.w, _wd[15], vd);           \
        va = dot2(h4.x, _wd[16], va); vb = dot2(h4.y, _wd[17], vb);           \
        vc = dot2(h4.z, _wd[18], vc); vd = dot2(h4.w, _wd[19], vd);           \
        va = dot2(h5.x, _wd[20], va); vb = dot2(h5.y, _wd[21], vb);           \
        vc = dot2(h5.z, _wd[22], vc); vd = dot2(h5.w, _wd[23], vd);           \
        va = dot2(h6.x, _wd[24], va); vb = dot2(h6.y, _wd[25], vb);           \
        vc = dot2(h6.z, _wd[26], vc); vd = dot2(h6.w, _wd[27], vd);           \
        va = dot2(h7.x, _wd[28], va); vb = dot2(h7.y, _wd[29], vb);           \
        vc = dot2(h7.z, _wd[30], vc); vd = dot2(h7.w, _wd[31], vd);           \
        float v = (va + vb) + (vc + vd);                                      \
        v = dpp_xor1_add(v);                                                  \
        float y = fmaxf(v, 0.f);                                              \
        if (kh == 0) {                                                        \
            unsigned short yb16 = f16bits(y);                                 \
            ((unsigned short*)&buf[P][l][0])[rsh] = yb16;                     \
            if (STORE)                                                        \
                ((unsigned short*)enc)[(size_t)(S) * 128 + rsh] = yb16;       \
        }                                                                     \
        BAR();                                                                \
    } while (0)

        for (int s = 0; s < T; s += 2) {
            SLOT_IH(0, 0, &buf[1][3][0], 0, s);
            SLOT_IH(1, 0, &buf[0][0][0], 0, s);
            SLOT_IH(2, 0, &buf[0][1][0], 0, s);
            SLOT_IH(3, 0, &buf[0][2][0], 1, s);
            SLOT_IH(0, 1, &buf[0][3][0], 0, s + 1);
            SLOT_IH(1, 1, &buf[1][0][0], 0, s + 1);
            SLOT_IH(2, 1, &buf[1][1][0], 0, s + 1);
            SLOT_IH(3, 1, &buf[1][2][0], 1, s + 1);
        }
#undef SLOT_IH
    } else {
        // ============ HH waves: shadow MFMA chain (matrix pipe) ==========
        const int m = lane & 15;    // A row-in-tile / D col
        const int g = lane >> 4;    // k-group / D row-quad

        f16x8 hhA[4][2][4];         // [layer][tile][ktile] resident Whh frags
        #pragma unroll
        for (int l = 0; l < 4; ++l)
            #pragma unroll
            for (int t = 0; t < 2; ++t) {
                const int row = w * 32 + t * 16 + m;
                #pragma unroll
                for (int kt = 0; kt < 4; ++kt) {
                    const float* p = Whh + ((size_t)(l * 128 + row)) * 128
                                         + kt * 32 + g * 8;
                    f16x8 v;
                    #pragma unroll
                    for (int e = 0; e < 8; ++e) v[e] = (f16)p[e];
                    hhA[l][t][kt] = v;
                }
            }

        f16x8 pfA[4], pfB[4];
        f32x4 pdA0, pdA1, pdB0, pdB1;

        // prologue: pre[0] = Whh_0 . x (raw); pending pdA (-> pre[1]) = 0;
        // prefetch pfA from buf[1][2] (zeros) for slot 0's MFMA (-> pre[2]).
        {
            const u32* sb = &buf[1][0][0];
            f16x8 j0 = *(const f16x8*)(sb + 0 * 16 + g * 4);
            f16x8 j1 = *(const f16x8*)(sb + 1 * 16 + g * 4);
            f16x8 j2 = *(const f16x8*)(sb + 2 * 16 + g * 4);
            f16x8 j3 = *(const f16x8*)(sb + 3 * 16 + g * 4);
            f32x4 t0 = MFMA(hhA[0][0][0], j0, ZERO4);
            t0 = MFMA(hhA[0][0][1], j1, t0);
            t0 = MFMA(hhA[0][0][2], j2, t0);
            t0 = MFMA(hhA[0][0][3], j3, t0);
            f32x4 t1 = MFMA(hhA[0][1][0], j0, ZERO4);
            t1 = MFMA(hhA[0][1][1], j1, t1);
            t1 = MFMA(hhA[0][1][2], j2, t1);
            t1 = MFMA(hhA[0][1][3], j3, t1);
            if (m == 0) {
                *(f32x4*)&pre[0][w * 32 + g * 4] = t0;
                *(f32x4*)&pre[0][w * 32 + 16 + g * 4] = t1;
            }
            pdA0 = ZERO4;
            pdA1 = ZERO4;
            const u32* pb = &buf[1][2][0];
            #pragma unroll
            for (int kt = 0; kt < 4; ++kt)
                pfA[kt] = *(const f16x8*)(pb + kt * 16 + g * 4);
        }
        BAR();   // matches IH post-weight-load barrier

        // slot: write pending -> pre[LW]; MFMA layer LC on PF_USE -> new
        // pending; prefetch PF_NEW from CURB (same buffer IH reads now).
#define SLOT_HH(LW, LC, PDW0, PDW1, PDN0, PDN1, PF_USE, PF_NEW, CURB) do {    \
        if (m == 0) {                                                         \
            *(f32x4*)&pre[LW][w * 32 + g * 4] = PDW0;                         \
            *(f32x4*)&pre[LW][w * 32 + 16 + g * 4] = PDW1;                    \
        }                                                                     \
        PDN0 = MFMA(hhA[LC][0][0], PF_USE[0], ZERO4);                         \
        PDN0 = MFMA(hhA[LC][0][1], PF_USE[1], PDN0);                          \
        PDN0 = MFMA(hhA[LC][0][2], PF_USE[2], PDN0);                          \
        PDN0 = MFMA(hhA[LC][0][3], PF_USE[3], PDN0);                          \
        PDN1 = MFMA(hhA[LC][1][0], PF_USE[0], ZERO4);                         \
        PDN1 = MFMA(hhA[LC][1][1], PF_USE[1], PDN1);                          \
        PDN1 = MFMA(hhA[LC][1][2], PF_USE[2], PDN1);                          \
        PDN1 = MFMA(hhA[LC][1][3], PF_USE[3], PDN1);                          \
        const u32* _pb = (CURB);                                              \
        PF_NEW[0] = *(const f16x8*)(_pb + 0 * 16 + g * 4);                    \
        PF_NEW[1] = *(const f16x8*)(_pb + 1 * 16 + g * 4);                    \
        PF_NEW[2] = *(const f16x8*)(_pb + 2 * 16 + g * 4);                    \
        PF_NEW[3] = *(const f16x8*)(_pb + 3 * 16 + g * 4);                    \
        BAR();                                                                \
    } while (0)

        for (int s = 0; s < T; s += 2) {
            SLOT_HH(1, 2, pdA0, pdA1, pdB0, pdB1, pfA, pfB, &buf[1][3][0]);
            SLOT_HH(2, 3, pdB0, pdB1, pdA0, pdA1, pfB, pfA, &buf[0][0][0]);
            SLOT_HH(3, 0, pdA0, pdA1, pdB0, pdB1, pfA, pfB, &buf[0][1][0]);
            SLOT_HH(0, 1, pdB0, pdB1, pdA0, pdA1, pfB, pfA, &buf[0][2][0]);
            SLOT_HH(1, 2, pdA0, pdA1, pdB0, pdB1, pfA, pfB, &buf[0][3][0]);
            SLOT_HH(2, 3, pdB0, pdB1, pdA0, pdA1, pfB, pfA, &buf[1][0][0]);
            SLOT_HH(3, 0, pdA0, pdA1, pdB0, pdB1, pfA, pfB, &buf[1][1][0]);
            SLOT_HH(0, 1, pdB0, pdB1, pdA0, pdA1, pfB, pfA, &buf[1][2][0]);
        }
#undef SLOT_HH
    }
}

// ---------------------------------------------------------------------------
// Heads kernel: grid (3 heads, T/32 row-segments), 256 threads. (unchanged)
// ---------------------------------------------------------------------------
__global__ __launch_bounds__(256) void heads_kernel(
    const u32* __restrict__ enc,
    const float* __restrict__ arw, const float* __restrict__ arb,
    const float* __restrict__ aw,  const float* __restrict__ ab,
    const float* __restrict__ prw, const float* __restrict__ prb,
    const float* __restrict__ pw,  const float* __restrict__ pb,
    const float* __restrict__ mrw, const float* __restrict__ mrb,
    const float* __restrict__ mw,  const float* __restrict__ mb,
    float* __restrict__ out, int T)
{
    const int head = blockIdx.x;
    const int r0 = blockIdx.y * 32;
    if (r0 >= T) return;

    const float *rbw, *rbb, *ow, *ob;
    int od, oc;
    if (head == 0)      { rbw = arw; rbb = arb; ow = aw; ob = ab; od = 8; oc = 0; }
    else if (head == 1) { rbw = prw; rbb = prb; ow = pw; ob = pb; od = 1; oc = 8; }
    else                { rbw = mrw; rbb = mrb; ow = mw; ob = mb; od = 1; oc = 9; }

    __shared__ u32 xs[32][64];
    __shared__ u32 hs[32][64];

    const int tid = threadIdx.x;

    #pragma unroll
    for (int rep = 0; rep < 8; ++rep) {
        int u = tid + rep * 256;
        int row = u >> 6, p = u & 63;
        xs[row][p] = enc[(size_t)(r0 + row) * 64 + p];
    }
    __syncthreads();

    const int j = tid & 127;
    const int rh = tid >> 7;

    float acc[16];
    u32 wreg[64];

#define PACKW(WPTR) do {                                                    \
        const float* _w = (WPTR);                                           \
        _Pragma("unroll")                                                   \
        for (int cc = 0; cc < 16; ++cc) {                                   \
            float4 aa = *(const float4*)(_w + cc * 8);                      \
            float4 bb = *(const float4*)(_w + cc * 8 + 4);                  \
            wreg[cc * 4 + 0] = pack2(aa.x, aa.y);                           \
            wreg[cc * 4 + 1] = pack2(aa.z, aa.w);                           \
            wreg[cc * 4 + 2] = pack2(bb.x, bb.y);                           \
            wreg[cc * 4 + 3] = pack2(bb.z, bb.w);                           \
        }                                                                   \
    } while (0)

#define MM16(SRC) do {                                                      \
        _Pragma("unroll")                                                   \
        for (int r = 0; r < 16; ++r) acc[r] = 0.f;                          \
        _Pragma("unroll")                                                   \
        for (int kp = 0; kp < 16; ++kp) {                                   \
            u32 w0 = wreg[kp * 4 + 0], w1 = wreg[kp * 4 + 1];               \
            u32 w2 = wreg[kp * 4 + 2], w3 = wreg[kp * 4 + 3];               \
            _Pragma("unroll")                                               \
            for (int r = 0; r < 16; ++r) {                                  \
                uint4 x4 = *(const uint4*)(&SRC[rh * 16 + r][kp * 4]);      \
                acc[r] = dot2(x4.x, w0, acc[r]);                            \
                acc[r] = dot2(x4.y, w1, acc[r]);                            \
                acc[r] = dot2(x4.z, w2, acc[r]);                            \
                acc[r] = dot2(x4.w, w3, acc[r]);                            \
            }                                                               \
        }                                                                   \
    } while (0)

    #pragma unroll
    for (int blk = 0; blk < 2; ++blk) {
        PACKW(rbw + (size_t)((blk * 2 + 0) * 128 + j) * 128);
        MM16(xs);
        {
            float b1 = rbb[(blk * 2 + 0) * 128 + j];
            #pragma unroll
            for (int r = 0; r < 16; ++r) {
                float v = acc[r] + b1;
                v = fmaxf(v, 0.2f * v);
                reinterpret_cast<unsigned short*>(&hs[rh * 16 + r][0])[j] = f16bits(v);
            }
        }
        __syncthreads();

        PACKW(rbw + (size_t)((blk * 2 + 1) * 128 + j) * 128);
        MM16(hs);
        {
            float b2 = rbb[(blk * 2 + 1) * 128 + j];
            #pragma unroll
            for (int r = 0; r < 16; ++r) {
                int row = rh * 16 + r;
                unsigned short xb =
                    reinterpret_cast<const unsigned short*>(&xs[row][0])[j];
                float xold = (float)__builtin_bit_cast(f16, xb);
                float v = xold + acc[r] + b2;
                v = fmaxf(v, 0.2f * v);
                reinterpret_cast<unsigned short*>(&xs[row][0])[j] = f16bits(v);
            }
        }
        __syncthreads();
    }

    {
        const int o = tid & 15;
        const int rr = tid >> 4;
        if (o < od) {
            PACKW(ow + (size_t)o * 128);
            float obv = ob[o];
            #pragma unroll
            for (int rs = 0; rs < 2; ++rs) {
                const int row = rr * 2 + rs;
                float a = 0.f;
                #pragma unroll
                for (int kp = 0; kp < 64; ++kp) a = dot2(xs[row][kp], wreg[kp], a);
                out[(size_t)(r0 + row) * 10 + oc + o] = a + obv;
            }
        }
    }
#undef PACKW
#undef MM16
}

extern "C" void kernel_launch(void* const* d_in, const int* in_sizes, int n_in,
                              void* d_out, int out_size, void* d_ws, size_t ws_size,
                              hipStream_t stream)
{
    const float* x   = (const float*)d_in[0];
    const float* Wih = (const float*)d_in[1];
    const float* Whh = (const float*)d_in[2];
    const float* bih = (const float*)d_in[3];
    const float* bhh = (const float*)d_in[4];
    const float* arw = (const float*)d_in[5];
    const float* arb = (const float*)d_in[6];
    const float* aw  = (const float*)d_in[7];
    const float* ab  = (const float*)d_in[8];
    const float* prw = (const float*)d_in[9];
    const float* prb = (const float*)d_in[10];
    const float* pw  = (const float*)d_in[11];
    const float* pb  = (const float*)d_in[12];
    const float* mrw = (const float*)d_in[13];
    const float* mrb = (const float*)d_in[14];
    const float* mw  = (const float*)d_in[15];
    const float* mb  = (const float*)d_in[16];

    const int T = out_size / 10;             // 32768
    u32* enc = (u32*)d_ws;                   // T*64 u32 (f16 pairs) = 8 MB

    rnn_kernel<<<1, 512, 0, stream>>>(x, Wih, Whh, bih, bhh, enc, T);

    heads_kernel<<<dim3(3, (T + 31) / 32), 256, 0, stream>>>(
        enc, arw, arb, aw, ab, prw, prb, pw, pb, mrw, mrb, mw, mb,
        (float*)d_out, T);
}